// Round 2
// baseline (444.978 us; speedup 1.0000x reference)
//
#include <hip/hip_runtime.h>
#include <math.h>

#define NTOK   8192
#define DIM    4096
#define NEXP   64
#define TOPK_N 8
#define TPW    4      // tokens per wave
#define WAVES  4      // waves per block -> 16 tokens per block
#define KC     128    // k elements staged per chunk
#define TAU    3.0e-4f
#define MAXFLAG 4096

// ---------------- Pass 1: fp32 GEMV + softmax + top-9 gap screen ----------------
__global__ __launch_bounds__(256, 2)
void gate_kernel(const float* __restrict__ x, const float* __restrict__ w,
                 const float* __restrict__ bias, float* __restrict__ out,
                 int* __restrict__ flags, int ntok) {
    __shared__ float4 lw[(KC / 4) * NEXP];   // 32 KiB, XOR-swizzled

    const int tid  = threadIdx.x;
    const int lane = tid & 63;
    const int wave = tid >> 6;
    const int tok0 = __builtin_amdgcn_readfirstlane(blockIdx.x * (WAVES * TPW) + wave * TPW);

    float acc[TPW] = {0.f, 0.f, 0.f, 0.f};

    for (int k0 = 0; k0 < DIM; k0 += KC) {
        __syncthreads();
        #pragma unroll
        for (int i = 0; i < (KC / 4) * NEXP / 256; ++i) {
            const int k4 = tid & 31;
            const int e  = i * 8 + (tid >> 5);
            const float4 v = *reinterpret_cast<const float4*>(
                w + (size_t)e * DIM + k0 + k4 * 4);
            lw[k4 * NEXP + (e ^ k4)] = v;
        }
        __syncthreads();

        #pragma unroll 4
        for (int j4 = 0; j4 < KC / 4; ++j4) {
            const float4 wv = lw[j4 * NEXP + (lane ^ j4)];
            #pragma unroll
            for (int t = 0; t < TPW; ++t) {
                const float4 xv = *reinterpret_cast<const float4*>(
                    x + (size_t)(tok0 + t) * DIM + k0 + j4 * 4);
                acc[t] = fmaf(xv.x, wv.x, acc[t]);
                acc[t] = fmaf(xv.y, wv.y, acc[t]);
                acc[t] = fmaf(xv.z, wv.z, acc[t]);
                acc[t] = fmaf(xv.w, wv.w, acc[t]);
            }
        }
    }

    const float bmy = bias[lane];
    float* __restrict__ out_idx = out + (size_t)NTOK * NEXP;

    #pragma unroll
    for (int t = 0; t < TPW; ++t) {
        const int tok = tok0 + t;
        if (tok >= ntok) break;
        const float s = acc[t] + bmy;

        // softmax across 64 lanes (lane = expert)
        float m = s;
        #pragma unroll
        for (int off = 32; off > 0; off >>= 1)
            m = fmaxf(m, __shfl_xor(m, off, 64));
        const float ex = expf(s - m);
        float sum = ex;
        #pragma unroll
        for (int off = 32; off > 0; off >>= 1)
            sum += __shfl_xor(sum, off, 64);
        out[(size_t)tok * NEXP + lane] = ex / sum;

        // top-9 extraction: write top-8 indices, track min adjacent gap among ranks 0..8
        float cv = s;
        float prev = 0.f;
        float ming = 1e30f;
        for (int r = 0; r < TOPK_N + 1; ++r) {
            float bv = cv;
            int   bi = lane;
            #pragma unroll
            for (int off = 32; off > 0; off >>= 1) {
                const float ov = __shfl_xor(bv, off, 64);
                const int   oi = __shfl_xor(bi, off, 64);
                if (ov > bv || (ov == bv && oi < bi)) { bv = ov; bi = oi; }
            }
            if (r > 0) ming = fminf(ming, prev - bv);
            prev = bv;
            if (r < TOPK_N && lane == r)
                out_idx[(size_t)tok * TOPK_N + r] = (float)bi;
            if (lane == bi)
                cv = -INFINITY;
        }

        // near-tie anywhere in ranks 0..8 -> flag token for fp64 recheck
        if (lane == 0 && ming < TAU) {
            const int slot = atomicAdd(flags, 1);
            if (slot < MAXFLAG) flags[1 + slot] = tok;
        }
    }
}

// ---------------- Pass 2: fp64 exact recheck of flagged tokens ----------------
__global__ __launch_bounds__(256, 4)
void recheck_kernel(const float* __restrict__ x, const float* __restrict__ w,
                    const float* __restrict__ bias, float* __restrict__ out,
                    const int* __restrict__ flags) {
    __shared__ double part[WAVES][NEXP];
    int n = flags[0];
    if (n > MAXFLAG) n = MAXFLAG;
    const int lane = threadIdx.x & 63;
    const int wv   = threadIdx.x >> 6;
    float* __restrict__ out_idx = out + (size_t)NTOK * NEXP;

    for (int i = blockIdx.x; i < n; i += gridDim.x) {
        const int tok = flags[1 + i];
        const float* xr = x + (size_t)tok * DIM + wv * (DIM / WAVES);
        const float* wr = w + (size_t)lane * DIM + wv * (DIM / WAVES);
        double acc = 0.0;
        #pragma unroll 4
        for (int k = 0; k < DIM / WAVES; k += 4) {
            const float4 xv  = *reinterpret_cast<const float4*>(xr + k);
            const float4 wv4 = *reinterpret_cast<const float4*>(wr + k);
            acc = fma((double)xv.x, (double)wv4.x, acc);
            acc = fma((double)xv.y, (double)wv4.y, acc);
            acc = fma((double)xv.z, (double)wv4.z, acc);
            acc = fma((double)xv.w, (double)wv4.w, acc);
        }
        part[wv][lane] = acc;
        __syncthreads();
        if (wv == 0) {
            // fixed-order combine -> deterministic
            double s = (((part[0][lane] + part[1][lane]) + part[2][lane]) + part[3][lane])
                       + (double)bias[lane];
            double cv = s;
            for (int r = 0; r < TOPK_N; ++r) {
                double bv = cv;
                int    bi = lane;
                #pragma unroll
                for (int off = 32; off > 0; off >>= 1) {
                    const double ov = __shfl_xor(bv, off, 64);
                    const int    oi = __shfl_xor(bi, off, 64);
                    if (ov > bv || (ov == bv && oi < bi)) { bv = ov; bi = oi; }
                }
                if (lane == r)
                    out_idx[(size_t)tok * TOPK_N + r] = (float)bi;
                if (lane == bi)
                    cv = -HUGE_VAL;
            }
        }
        __syncthreads();
    }
}

extern "C" void kernel_launch(void* const* d_in, const int* in_sizes, int n_in,
                              void* d_out, int out_size, void* d_ws, size_t ws_size,
                              hipStream_t stream) {
    const float* x  = (const float*)d_in[0];
    const float* w  = (const float*)d_in[1];
    const float* bs = (const float*)d_in[2];
    float* out = (float*)d_out;
    int*   flags = (int*)d_ws;

    const int ntok = in_sizes[0] / DIM;                            // 8192
    const int tok_per_block = WAVES * TPW;                         // 16
    const int grid = (ntok + tok_per_block - 1) / tok_per_block;   // 512

    // zero the flag counter (ws is poisoned to 0xAA before every call)
    hipMemsetAsync(flags, 0, sizeof(int), stream);

    hipLaunchKernelGGL(gate_kernel, dim3(grid), dim3(256), 0, stream,
                       x, w, bs, out, flags, ntok);
    hipLaunchKernelGGL(recheck_kernel, dim3(512), dim3(256), 0, stream,
                       x, w, bs, out, flags);
}